// Round 12
// baseline (197.827 us; speedup 1.0000x reference)
//
#include <hip/hip_runtime.h>

#define N_NODES 50000
#define N_EDGES 800000
#define DIM 128
#define H 8
#define PAD 64          // max stored in-degree; deg~Poisson(16), P(>64)~1e-21. Guarded.
#define NPART 256       // dst partitions
#define PART_NODES 196  // ceil(50000/256); NPART*PART_NODES = 50176
#define PART_CAP 4096   // entries per partition region (mean 3125, +17 sigma)
#define EPB 2048        // edges per k_part block

typedef unsigned short ushort_t;
typedef unsigned int uint_t;
typedef __attribute__((ext_vector_type(8))) short bf16x8;
typedef __attribute__((ext_vector_type(4))) float f32x4;

__device__ __forceinline__ float bf2f(ushort_t u) {
    return __uint_as_float(((uint_t)u) << 16);
}
__device__ __forceinline__ ushort_t f2bf(float f) {
    uint_t x = __float_as_uint(f);
    uint_t r = (x + 0x7FFFu + ((x >> 16) & 1u)) >> 16;   // RNE
    return (ushort_t)r;
}

// ---------------------------------------------------------------------------
// One-time W transpose + SPLIT bf16: Thi[n][k]=bf16(W[k][n]), Tlo=residual.
// ---------------------------------------------------------------------------
__global__ __launch_bounds__(256) void k_wtrans(
    const float* __restrict__ Wa, const float* __restrict__ Wb,
    ushort_t* __restrict__ Tahi, ushort_t* __restrict__ Talo,
    ushort_t* __restrict__ Tbhi, ushort_t* __restrict__ Tblo)
{
    __shared__ ushort_t th[16 * 136];
    __shared__ ushort_t tl[16 * 136];
    const int b = blockIdx.x, t = threadIdx.x;
    const float* Win = (b < 8) ? Wa : Wb;
    ushort_t* Thi = (b < 8) ? Tahi : Tbhi;
    ushort_t* Tlo = (b < 8) ? Talo : Tblo;
    const int n0 = (b & 7) * 16;

    #pragma unroll
    for (int rep = 0; rep < 2; ++rep) {
        int k = rep * 64 + (t >> 2);
        int c = (t & 3) * 4;
        float4 v = *(const float4*)(Win + (size_t)k * DIM + n0 + c);
        float vv[4] = {v.x, v.y, v.z, v.w};
        #pragma unroll
        for (int j = 0; j < 4; ++j) {
            ushort_t hi = f2bf(vv[j]);
            ushort_t lo = f2bf(vv[j] - bf2f(hi));
            th[(c + j) * 136 + k] = hi;
            tl[(c + j) * 136 + k] = lo;
        }
    }
    __syncthreads();
    {
        int j = t >> 4;          // 0..15
        int c = (t & 15) * 8;    // 0..120
        *(bf16x8*)(Thi + (size_t)(n0 + j) * DIM + c) = *(const bf16x8*)(th + j * 136 + c);
        *(bf16x8*)(Tlo + (size_t)(n0 + j) * DIM + c) = *(const bf16x8*)(tl + j * 136 + c);
    }
}

// ---------------------------------------------------------------------------
// MFMA GEMM, split-A x split-W: Y = (Ahi+Alo)@(Whi+Wlo) + bias, dropping the
// O(2^-18) Alo@Wlo term -> 96 MFMAs/wave. A from LN(X) (DO_LN) or fp32 Af.
// W tiles staged per 64-k half with XOR swizzle (conflict-free b128 R/W).
// A-frag (16x16x32): m=lane&15, k=(lane>>4)*8+j. C/D: col=lane&15, row=q*4+reg.
// DO_SCORES fuses su/sv epilogue and zeroes pcount (block 0).
// ---------------------------------------------------------------------------
template<bool DO_LN, bool BF16_OUT, bool DO_SCORES>
__global__ __launch_bounds__(256) void k_gemm_mfma(
    const float* __restrict__ X, const float* __restrict__ Af,
    const ushort_t* __restrict__ Whi, const ushort_t* __restrict__ Wlo,
    const float* __restrict__ bias,
    const float* __restrict__ gamma, const float* __restrict__ beta,
    const float* __restrict__ W_u, const float* __restrict__ b_u,
    const float* __restrict__ W_v,
    float* __restrict__ Yf, ushort_t* __restrict__ Yb,
    float* __restrict__ su, float* __restrict__ sv,
    int* __restrict__ pcount)
{
    __shared__ ushort_t wh[128 * 64];      // 16 KB: hi tile, one 64-k half
    __shared__ ushort_t wl[128 * 64];      // 16 KB: lo tile
    __shared__ float    wuvT[2][8 * 128];  // 8 KB

    const int t  = threadIdx.x;
    const int n0 = blockIdx.x * 64;
    const int l  = t & 63, w = t >> 6;
    const int m  = l & 15, q = l >> 4;

    if (DO_SCORES && blockIdx.x == 0) pcount[t] = 0;   // t<256 == NPART

    if (DO_SCORES) {
        #pragma unroll
        for (int i = 0; i < 8; ++i) {
            int g = i * 256 + t;
            int sel = g >> 10;
            int rem = g & 1023;
            int col = rem >> 3, h = rem & 7;
            float v = sel ? W_v[rem] : W_u[rem];
            wuvT[sel][h * 128 + col] = v;
        }
    }

    // ---- Build split A-fragments (no LDS dependency)
    const int node = n0 + w * 16 + m;
    const int nc   = (node < N_NODES) ? node : (N_NODES - 1);
    bf16x8 afh[4], afl[4];

    if (DO_LN) {
        const float* xrow = X + (size_t)nc * DIM;
        float xv[4][8];
        float s = 0.f, ss = 0.f;
        #pragma unroll
        for (int ks = 0; ks < 4; ++ks) {
            int base = 32 * ks + 8 * q;
            float4 a0 = *(const float4*)(xrow + base);
            float4 a1 = *(const float4*)(xrow + base + 4);
            xv[ks][0]=a0.x; xv[ks][1]=a0.y; xv[ks][2]=a0.z; xv[ks][3]=a0.w;
            xv[ks][4]=a1.x; xv[ks][5]=a1.y; xv[ks][6]=a1.z; xv[ks][7]=a1.w;
            #pragma unroll
            for (int j = 0; j < 8; ++j) { s += xv[ks][j]; ss += xv[ks][j]*xv[ks][j]; }
        }
        s  += __shfl_xor(s, 16);  s  += __shfl_xor(s, 32);
        ss += __shfl_xor(ss, 16); ss += __shfl_xor(ss, 32);
        float mu   = s * (1.f / DIM);
        float var  = ss * (1.f / DIM) - mu * mu;
        float rstd = rsqrtf(var + 1e-5f);
        #pragma unroll
        for (int ks = 0; ks < 4; ++ks) {
            int base = 32 * ks + 8 * q;
            float4 g0 = *(const float4*)(gamma + base);
            float4 g1 = *(const float4*)(gamma + base + 4);
            float4 b0 = *(const float4*)(beta + base);
            float4 b1 = *(const float4*)(beta + base + 4);
            float gg[8] = {g0.x,g0.y,g0.z,g0.w,g1.x,g1.y,g1.z,g1.w};
            float bb[8] = {b0.x,b0.y,b0.z,b0.w,b1.x,b1.y,b1.z,b1.w};
            #pragma unroll
            for (int j = 0; j < 8; ++j) {
                float xn = (xv[ks][j] - mu) * rstd * gg[j] + bb[j];
                ushort_t hi = f2bf(xn);
                afh[ks][j] = (short)hi;
                afl[ks][j] = (short)f2bf(xn - bf2f(hi));
            }
        }
    } else {
        const float* arow = Af + (size_t)nc * DIM;
        #pragma unroll
        for (int ks = 0; ks < 4; ++ks) {
            int base = 32 * ks + 8 * q;
            float4 a0 = *(const float4*)(arow + base);
            float4 a1 = *(const float4*)(arow + base + 4);
            float av[8] = {a0.x,a0.y,a0.z,a0.w,a1.x,a1.y,a1.z,a1.w};
            #pragma unroll
            for (int j = 0; j < 8; ++j) {
                ushort_t hi = f2bf(av[j]);
                afh[ks][j] = (short)hi;
                afl[ks][j] = (short)f2bf(av[j] - bf2f(hi));
            }
        }
    }

    // ---- MFMA main: 2 k-halves x (stage hi+lo, 2 k-steps x 8 col-tiles x 3)
    f32x4 acc[8];
    #pragma unroll
    for (int c = 0; c < 8; ++c) acc[c] = (f32x4){0.f, 0.f, 0.f, 0.f};

    for (int kc = 0; kc < 2; ++kc) {
        __syncthreads();   // prior-half reads done (first: wuvT staging fence)
        #pragma unroll
        for (int rep = 0; rep < 4; ++rep) {
            int id = rep * 256 + t;          // 0..1023
            int n  = id >> 3;                // 0..127
            int kb = id & 7;                 // 0..7 (local 8-k chunk)
            size_t goff = (size_t)n * DIM + kc * 64 + kb * 8;
            int loff = n * 64 + ((kb ^ (n & 7)) << 3);
            *(bf16x8*)(wh + loff) = *(const bf16x8*)(Whi + goff);
            *(bf16x8*)(wl + loff) = *(const bf16x8*)(Wlo + goff);
        }
        __syncthreads();

        #pragma unroll
        for (int ks2 = 0; ks2 < 2; ++ks2) {
            bf16x8 ah = afh[kc * 2 + ks2];
            bf16x8 al = afl[kc * 2 + ks2];
            int sb = ks2 * 4 + q;            // local k-chunk of this lane's B-frag
            #pragma unroll
            for (int c = 0; c < 8; ++c) {
                int n = c * 16 + m;
                int loff = n * 64 + ((sb ^ (n & 7)) << 3);
                bf16x8 blo = *(const bf16x8*)(wl + loff);
                bf16x8 bhi = *(const bf16x8*)(wh + loff);
                acc[c] = __builtin_amdgcn_mfma_f32_16x16x32_bf16(al, bhi, acc[c], 0, 0, 0);
                acc[c] = __builtin_amdgcn_mfma_f32_16x16x32_bf16(ah, blo, acc[c], 0, 0, 0);
                acc[c] = __builtin_amdgcn_mfma_f32_16x16x32_bf16(ah, bhi, acc[c], 0, 0, 0);
            }
        }
    }

    // ---- Epilogue: per r, node nn = n0 + w*16 + q*4 + r; col = c*16 + m
    float bcol[8];
    #pragma unroll
    for (int c = 0; c < 8; ++c) bcol[c] = bias[c * 16 + m];

    #pragma unroll
    for (int r = 0; r < 4; ++r) {
        int nn = n0 + w * 16 + q * 4 + r;
        bool ok = (nn < N_NODES);
        float v[8];
        #pragma unroll
        for (int c = 0; c < 8; ++c) v[c] = acc[c][r] + bcol[c];

        if (ok) {
            #pragma unroll
            for (int c = 0; c < 8; ++c) {
                int col = c * 16 + m;
                if (BF16_OUT) Yb[(size_t)nn * DIM + col] = f2bf(v[c]);
                else          Yf[(size_t)nn * DIM + col] = v[c];
            }
        }

        if (DO_SCORES) {
            float ps[16];
            #pragma unroll
            for (int h = 0; h < 8; ++h) {
                float a = 0.f, b = 0.f;
                #pragma unroll
                for (int c = 0; c < 8; ++c) {
                    int col = c * 16 + m;
                    a += v[c] * wuvT[0][h * 128 + col];
                    b += v[c] * wuvT[1][h * 128 + col];
                }
                ps[h] = a; ps[8 + h] = b;
            }
            #pragma unroll
            for (int o = 1; o < 16; o <<= 1) {
                #pragma unroll
                for (int j = 0; j < 16; ++j) ps[j] += __shfl_xor(ps[j], o);
            }
            if (ok) {
                if (m < 8) su[nn * H + m] = ps[m] + b_u[m];
                else       sv[nn * H + (m - 8)] = ps[m];
            }
        }
    }
}

// ---------------------------------------------------------------------------
// Counting-sort pass 1 (unchanged): partition edges by dst/PART_NODES.
// ---------------------------------------------------------------------------
__global__ __launch_bounds__(256) void k_part(
    const int* __restrict__ src, const int* __restrict__ dst,
    int* __restrict__ pcount, uint_t* __restrict__ pbuf)
{
    __shared__ int hist[NPART];
    __shared__ int base[NPART];
    __shared__ uint_t rec[EPB];
    __shared__ ushort_t rnk[EPB];
    __shared__ unsigned char prt[EPB];

    const int t = threadIdx.x;
    const int e0 = blockIdx.x * EPB;
    hist[t] = 0;
    __syncthreads();

    #pragma unroll
    for (int i = 0; i < EPB / 256; ++i) {
        int idx = i * 256 + t;
        int e = e0 + idx;
        if (e < N_EDGES) {
            int s = src[e], d = dst[e];
            int p = d / PART_NODES;
            int dl = d - p * PART_NODES;
            int r = atomicAdd(&hist[p], 1);
            rec[idx] = ((uint_t)dl << 16) | (uint_t)s;
            rnk[idx] = (ushort_t)r;
            prt[idx] = (unsigned char)p;
        }
    }
    __syncthreads();
    base[t] = atomicAdd(&pcount[t], hist[t]);
    __syncthreads();

    #pragma unroll
    for (int i = 0; i < EPB / 256; ++i) {
        int idx = i * 256 + t;
        int e = e0 + idx;
        if (e < N_EDGES) {
            int p = prt[idx];
            int slot = base[p] + (int)rnk[idx];
            if (slot < PART_CAP)
                pbuf[(size_t)p * PART_CAP + slot] = rec[idx];
        }
    }
}

// ---------------------------------------------------------------------------
// Counting-sort pass 2 (unchanged): LDS bucket per partition, coalesced dump.
// ---------------------------------------------------------------------------
__global__ __launch_bounds__(256) void k_bucket(
    const uint_t* __restrict__ pbuf, const int* __restrict__ pcount,
    ushort_t* __restrict__ esrc_p, int* __restrict__ deg)
{
    __shared__ ushort_t buck[PART_NODES * PAD];   // 25088 B
    __shared__ int cnt[PART_NODES];

    const int p = blockIdx.x, t = threadIdx.x;
    for (int i = t; i < PART_NODES; i += 256) cnt[i] = 0;
    __syncthreads();

    const int m = min(pcount[p], PART_CAP);
    for (int i = t; i < m; i += 256) {
        uint_t v = pbuf[(size_t)p * PART_CAP + i];
        int dl = (int)(v >> 16);
        int pos = atomicAdd(&cnt[dl], 1);
        if (pos < PAD) buck[dl * PAD + pos] = (ushort_t)(v & 0xFFFF);
    }
    __syncthreads();

    const int n0 = p * PART_NODES;
    const uint_t* b32 = (const uint_t*)buck;
    uint_t* g32 = (uint_t*)(esrc_p + (size_t)n0 * PAD);
    for (int i = t; i < PART_NODES * PAD / 2; i += 256) g32[i] = b32[i];
    for (int i = t; i < PART_NODES; i += 256) {
        int n = n0 + i;
        if (n < N_NODES) deg[n] = cnt[i];
    }
}

// ---------------------------------------------------------------------------
// Softmax + aggregation, two-phase (R8 structure), fp32 agg output.
// ---------------------------------------------------------------------------
__global__ __launch_bounds__(128) void k_node_agg(
    const ushort_t* __restrict__ esrc_p, const int* __restrict__ deg,
    const float* __restrict__ su, const float* __restrict__ sv,
    const ushort_t* __restrict__ yb, float* __restrict__ agg)
{
    __shared__ float wls[2][PAD * 8];   // 4 KB: per node, w[edge][head]

    const int w = threadIdx.x >> 6, l = threadIdx.x & 63;
    const int n = blockIdx.x * 2 + w;
    const int d = min(deg[n], PAD);
    const int sl = (l < d) ? (int)esrc_p[(size_t)n * PAD + l] : 0;

    if (l < d) {
        float4 sva = *(const float4*)(sv + n * H);
        float4 svb = *(const float4*)(sv + n * H + 4);
        float4 sua = *(const float4*)(su + sl * H);
        float4 sub = *(const float4*)(su + sl * H + 4);
        float e[8] = {sua.x+sva.x, sua.y+sva.y, sua.z+sva.z, sua.w+sva.w,
                      sub.x+svb.x, sub.y+svb.y, sub.z+svb.z, sub.w+svb.w};
        float wv[8];
        #pragma unroll
        for (int h = 0; h < 8; ++h) {
            float ee = e[h];
            ee = (ee >= 0.f) ? ee : 0.2f * ee;
            wv[h] = __expf(ee);
        }
        *(float4*)(&wls[w][l * 8])     = make_float4(wv[0], wv[1], wv[2], wv[3]);
        *(float4*)(&wls[w][l * 8 + 4]) = make_float4(wv[4], wv[5], wv[6], wv[7]);
    }
    __syncthreads();

    const float* wrow = &wls[w][2 * (l & 3)];
    float ssum0 = 0.f, ssum1 = 0.f, acc0 = 0.f, acc1 = 0.f;
    int i = 0;
    for (; i + 4 <= d; i += 4) {
        int s0 = __shfl(sl, i);
        int s1 = __shfl(sl, i + 1);
        int s2 = __shfl(sl, i + 2);
        int s3 = __shfl(sl, i + 3);
        float2 w0 = *(const float2*)(wrow + (i    ) * 8);
        float2 w1 = *(const float2*)(wrow + (i + 1) * 8);
        float2 w2 = *(const float2*)(wrow + (i + 2) * 8);
        float2 w3 = *(const float2*)(wrow + (i + 3) * 8);
        uint_t y0 = *(const uint_t*)(yb + (size_t)s0 * DIM + 2 * l);
        uint_t y1 = *(const uint_t*)(yb + (size_t)s1 * DIM + 2 * l);
        uint_t y2 = *(const uint_t*)(yb + (size_t)s2 * DIM + 2 * l);
        uint_t y3 = *(const uint_t*)(yb + (size_t)s3 * DIM + 2 * l);

        ssum0 += (w0.x + w1.x) + (w2.x + w3.x);
        ssum1 += (w0.y + w1.y) + (w2.y + w3.y);
        acc0 += w0.x * __uint_as_float(y0 << 16) + w1.x * __uint_as_float(y1 << 16)
              + w2.x * __uint_as_float(y2 << 16) + w3.x * __uint_as_float(y3 << 16);
        acc1 += w0.y * __uint_as_float(y0 & 0xFFFF0000u) + w1.y * __uint_as_float(y1 & 0xFFFF0000u)
              + w2.y * __uint_as_float(y2 & 0xFFFF0000u) + w3.y * __uint_as_float(y3 & 0xFFFF0000u);
    }
    for (; i < d; ++i) {
        int s0 = __shfl(sl, i);
        float2 w0 = *(const float2*)(wrow + i * 8);
        uint_t y0 = *(const uint_t*)(yb + (size_t)s0 * DIM + 2 * l);
        ssum0 += w0.x; ssum1 += w0.y;
        acc0 += w0.x * __uint_as_float(y0 << 16);
        acc1 += w0.y * __uint_as_float(y0 & 0xFFFF0000u);
    }
    float r0 = (ssum0 > 0.f) ? (1.0f / ssum0) : 0.f;
    float r1 = (ssum1 > 0.f) ? (1.0f / ssum1) : 0.f;
    *(float2*)(agg + (size_t)n * DIM + 2 * l) = make_float2(acc0 * r0, acc1 * r1);
}

// ---------------------------------------------------------------------------
extern "C" void kernel_launch(void* const* d_in, const int* in_sizes, int n_in,
                              void* d_out, int out_size, void* d_ws, size_t ws_size,
                              hipStream_t stream)
{
    const float* x     = (const float*)d_in[0];
    const int*   src   = (const int*)  d_in[1];
    const int*   dst   = (const int*)  d_in[2];
    const float* gamma = (const float*)d_in[3];
    const float* beta  = (const float*)d_in[4];
    const float* W_in  = (const float*)d_in[5];
    const float* b_in  = (const float*)d_in[6];
    const float* W_u   = (const float*)d_in[7];
    const float* b_u   = (const float*)d_in[8];
    const float* W_v   = (const float*)d_in[9];
    const float* W_ff  = (const float*)d_in[10];
    const float* b_ff  = (const float*)d_in[11];
    float* out = (float*)d_out;

    char* ws = (char*)d_ws;
    ushort_t* yb     = (ushort_t*)ws; ws += (size_t)N_NODES * DIM * 2;
    float* agg       = (float*)ws; ws += (size_t)N_NODES * DIM * 4;
    float* su        = (float*)ws; ws += (size_t)N_NODES * H * 4;
    float* sv        = (float*)ws; ws += (size_t)N_NODES * H * 4;
    int*   deg       = (int*)  ws; ws += (size_t)N_NODES * 4;
    int*   pcount    = (int*)  ws; ws += (size_t)NPART * 4;
    uint_t* pbuf     = (uint_t*)ws; ws += (size_t)NPART * PART_CAP * 4;
    ushort_t* esrc_p = (ushort_t*)ws; ws += (size_t)NPART * PART_NODES * PAD * 2;
    ushort_t* wt_in_hi = (ushort_t*)ws; ws += (size_t)DIM * DIM * 2;
    ushort_t* wt_in_lo = (ushort_t*)ws; ws += (size_t)DIM * DIM * 2;
    ushort_t* wt_ff_hi = (ushort_t*)ws; ws += (size_t)DIM * DIM * 2;
    ushort_t* wt_ff_lo = (ushort_t*)ws; ws += (size_t)DIM * DIM * 2;

    const int NB_PART = (N_EDGES + EPB - 1) / EPB;   // 391
    const int NB_GEMM = (N_NODES + 63) / 64;         // 782

    hipLaunchKernelGGL(k_wtrans, dim3(16), dim3(256), 0, stream,
                       W_in, W_ff, wt_in_hi, wt_in_lo, wt_ff_hi, wt_ff_lo);
    hipLaunchKernelGGL((k_gemm_mfma<true, true, true>), dim3(NB_GEMM), dim3(256), 0, stream,
                       x, (const float*)nullptr, wt_in_hi, wt_in_lo, b_in, gamma, beta,
                       W_u, b_u, W_v,
                       (float*)nullptr, yb, su, sv, pcount);
    hipLaunchKernelGGL(k_part, dim3(NB_PART), dim3(256), 0, stream,
                       src, dst, pcount, pbuf);
    hipLaunchKernelGGL(k_bucket, dim3(NPART), dim3(256), 0, stream,
                       pbuf, pcount, esrc_p, deg);
    hipLaunchKernelGGL(k_node_agg, dim3(N_NODES / 2), dim3(128), 0, stream,
                       esrc_p, deg, su, sv, yb, agg);
    hipLaunchKernelGGL((k_gemm_mfma<false, false, false>), dim3(NB_GEMM), dim3(256), 0, stream,
                       (const float*)nullptr, agg, wt_ff_hi, wt_ff_lo, b_ff,
                       (const float*)nullptr, (const float*)nullptr,
                       (const float*)nullptr, (const float*)nullptr, (const float*)nullptr,
                       out, (ushort_t*)nullptr, (float*)nullptr, (float*)nullptr,
                       (int*)nullptr);
}